// Round 4
// baseline (1720.803 us; speedup 1.0000x reference)
//
#include <hip/hip_runtime.h>

#define NN 100000
#define NE 1600000
#define SHIFT 7
#define BKN 128              // nodes per bucket
#define NBKT 782             // ceil(NN/128)
#define EPB 8192             // edges per k_bin block
#define NBB 196              // ceil(NE/EPB)

// ---- histogram: per-node degree (for dis) + per-bucket counts ----
__global__ __launch_bounds__(256) void k_hist(const int* __restrict__ dst,
                                              int* __restrict__ cnt,
                                              int* __restrict__ bcnt) {
  __shared__ int bh[NBKT];
  for (int i = threadIdx.x; i < NBKT; i += 256) bh[i] = 0;
  __syncthreads();
  for (int e = blockIdx.x * 256 + threadIdx.x; e < NE; e += gridDim.x * 256) {
    int t = dst[e];
    atomicAdd(&cnt[t], 1);
    atomicAdd(&bh[t >> SHIFT], 1);
  }
  __syncthreads();
  for (int i = threadIdx.x; i < NBKT; i += 256)
    if (bh[i]) atomicAdd(&bcnt[i], bh[i]);
}

__global__ __launch_bounds__(256) void k_dis(const int* __restrict__ cnt,
                                             float* __restrict__ dis) {
  int i = blockIdx.x * 256 + threadIdx.x;
  if (i < NN) dis[i] = rsqrtf((float)cnt[i] + 1.0f);  // deg+1 (self loop)
}

// ---- exclusive scan of 782 bucket counts (single block) ----
__global__ __launch_bounds__(1024) void k_bscan(const int* __restrict__ bcnt,
                                                int* __restrict__ gbase,
                                                int* __restrict__ gcur) {
  __shared__ int s[1024];
  int t = threadIdx.x;
  int v = (t < NBKT) ? bcnt[t] : 0;
  s[t] = v;
  __syncthreads();
  for (int off = 1; off < 1024; off <<= 1) {
    int u = (t >= off) ? s[t - off] : 0;
    __syncthreads();
    s[t] += u;
    __syncthreads();
  }
  if (t < NBKT) {
    int excl = s[t] - v;
    gbase[t] = excl;
    gcur[t] = excl;
  }
  if (t == 0) gbase[NBKT] = NE;
}

// ---- bin edges by dst bucket: packed = (dstLocal<<24)|src ----
__global__ __launch_bounds__(512) void k_bin(const int* __restrict__ src,
                                             const int* __restrict__ dst,
                                             int* __restrict__ gcur,
                                             unsigned* __restrict__ packed) {
  __shared__ int lc[NBKT];
  for (int i = threadIdx.x; i < NBKT; i += 512) lc[i] = 0;
  __syncthreads();
  const int base = blockIdx.x * EPB;
  const int end = (base + EPB < NE) ? base + EPB : NE;
  for (int e = base + threadIdx.x; e < end; e += 512)
    atomicAdd(&lc[dst[e] >> SHIFT], 1);
  __syncthreads();
  for (int i = threadIdx.x; i < NBKT; i += 512) {
    int c = lc[i];
    if (c) lc[i] = atomicAdd(&gcur[i], c);  // lc becomes running global cursor
  }
  __syncthreads();
  for (int e = base + threadIdx.x; e < end; e += 512) {
    int d = dst[e];
    int pos = atomicAdd(&lc[d >> SHIFT], 1);
    packed[pos] = ((unsigned)(d & (BKN - 1)) << 24) | (unsigned)src[e];
  }
}

// ---- 64x64 GEMM: hs = (in @ W) * dis ----
__global__ __launch_bounds__(256) void k_mm(const float* __restrict__ in,
                                            const float* __restrict__ W,
                                            const float* __restrict__ dis,
                                            float* __restrict__ hs) {
  __shared__ float Wl[64 * 64];
  for (int i = threadIdx.x; i < 64 * 64; i += 256) Wl[i] = W[i];
  __syncthreads();
  const int lane = threadIdx.x & 63;
  const int gw = (blockIdx.x * 256 + threadIdx.x) >> 6;
  const int nw = gridDim.x * 4;
  for (int row = gw; row < NN; row += nw) {
    float v = in[row * 64 + lane];
    float acc = 0.0f;
#pragma unroll
    for (int k = 0; k < 64; ++k)
      acc = fmaf(__shfl(v, k), Wl[k * 64 + lane], acc);
    hs[row * 64 + lane] = acc * dis[row];
  }
}

// ---- bucket aggregation: v = relu(dis[t]*(self + sum_src hs[s]) + b) ----
__global__ __launch_bounds__(512) void k_agg(const float* __restrict__ hs,
                                             const unsigned* __restrict__ packed,
                                             const int* __restrict__ gbase,
                                             const float* __restrict__ dis,
                                             const float* __restrict__ bvec,
                                             float* __restrict__ vout) {
  __shared__ float acc[BKN * 64];  // 32 KiB
  const int b = blockIdx.x;
  const int nbase = b << SHIFT;
  const int nIn = (NN - nbase < BKN) ? (NN - nbase) : BKN;
  const int tid = threadIdx.x;
  // init with self-loop term (hs already scaled by dis[src]=dis[t])
  for (int i = tid; i < nIn * 64; i += 512) acc[i] = hs[nbase * 64 + i];
  __syncthreads();
  const int ebase = gbase[b];
  const int ecnt = gbase[b + 1] - ebase;
  const int lane = tid & 63;
  const int w = tid >> 6;  // 8 waves
  for (int k0 = w * 8; k0 < ecnt; k0 += 64) {
    if (k0 + 8 <= ecnt) {
      unsigned pp[8];
#pragma unroll
      for (int j = 0; j < 8; ++j) pp[j] = packed[ebase + k0 + j];
      float aa[8];
#pragma unroll
      for (int j = 0; j < 8; ++j)
        aa[j] = hs[(pp[j] & 0x00FFFFFFu) * 64 + lane];
#pragma unroll
      for (int j = 0; j < 8; ++j)
        atomicAdd(&acc[(pp[j] >> 24) * 64 + lane], aa[j]);
    } else {
      for (int j = k0; j < ecnt; ++j) {
        unsigned p = packed[ebase + j];
        float a = hs[(p & 0x00FFFFFFu) * 64 + lane];
        atomicAdd(&acc[(p >> 24) * 64 + lane], a);
      }
    }
  }
  __syncthreads();
  for (int i = tid; i < nIn * 64; i += 512) {
    int row = i >> 6;
    vout[nbase * 64 + i] =
        fmaxf(fmaf(dis[nbase + row], acc[i], bvec[i & 63]), 0.0f);
  }
}

// ---- dense head: v2 -> relu(dense128) -> out2 ----
__global__ __launch_bounds__(256) void k_head(const float* __restrict__ v2,
                                              const float* __restrict__ Wd,
                                              const float* __restrict__ bd,
                                              const float* __restrict__ Wo,
                                              const float* __restrict__ bo,
                                              float* __restrict__ out) {
  __shared__ float Wdl[64 * 128];  // 32 KiB
  __shared__ float Wol[256];
  for (int i = threadIdx.x; i < 64 * 128; i += 256) Wdl[i] = Wd[i];
  if (threadIdx.x < 256) Wol[threadIdx.x] = Wo[threadIdx.x];
  __syncthreads();
  const int lane = threadIdx.x & 63;
  const int gw = (blockIdx.x * 256 + threadIdx.x) >> 6;
  const int nw = gridDim.x * 4;
  const float bd0 = bd[lane], bd1 = bd[lane + 64];
  const float bo0 = bo[0], bo1 = bo[1];
  for (int row = gw; row < NN; row += nw) {
    float v = v2[row * 64 + lane];  // already relu'd
    float t0 = bd0, t1 = bd1;
#pragma unroll
    for (int k = 0; k < 64; ++k) {
      const float xk = __shfl(v, k);
      t0 = fmaf(xk, Wdl[k * 128 + lane], t0);
      t1 = fmaf(xk, Wdl[k * 128 + 64 + lane], t1);
    }
    t0 = fmaxf(t0, 0.0f);
    t1 = fmaxf(t1, 0.0f);
    float o0 = fmaf(t0, Wol[lane * 2 + 0], t1 * Wol[(lane + 64) * 2 + 0]);
    float o1 = fmaf(t0, Wol[lane * 2 + 1], t1 * Wol[(lane + 64) * 2 + 1]);
#pragma unroll
    for (int off = 32; off > 0; off >>= 1) {
      o0 += __shfl_down(o0, off);
      o1 += __shfl_down(o1, off);
    }
    if (lane == 0) {
      out[row * 2 + 0] = o0 + bo0;
      out[row * 2 + 1] = o1 + bo1;
    }
  }
}

extern "C" void kernel_launch(void* const* d_in, const int* in_sizes, int n_in,
                              void* d_out, int out_size, void* d_ws, size_t ws_size,
                              hipStream_t stream) {
  const float* x  = (const float*)d_in[0];
  const int*   ei = (const int*)d_in[1];
  const float* W1 = (const float*)d_in[2];
  const float* b1 = (const float*)d_in[3];
  const float* W2 = (const float*)d_in[4];
  const float* b2 = (const float*)d_in[5];
  const float* Wd = (const float*)d_in[6];
  const float* bd = (const float*)d_in[7];
  const float* Wo = (const float*)d_in[8];
  const float* bo = (const float*)d_in[9];
  float* out = (float*)d_out;

  const int* src = ei;        // edge_index[0]
  const int* dst = ei + NE;   // edge_index[1]

  // workspace layout (4 B units)
  char* ws = (char*)d_ws;
  int*      cnt    = (int*)(ws);                    // [0, 102400)
  int*      bcnt   = (int*)(ws + 102400L * 4);      // 1024
  int*      gbase  = (int*)(ws + 103424L * 4);      // 1024 (NBKT+1 used)
  int*      gcur   = (int*)(ws + 104448L * 4);      // 1024
  float*    dis    = (float*)(ws + 105472L * 4);    // 102400
  unsigned* packed = (unsigned*)(ws + 207872L * 4); // NE
  float*    hs     = (float*)(ws + 1807872L * 4);   // NN*64
  float*    vbuf   = (float*)(ws + 8207872L * 4);   // NN*64

  // zero cnt + bcnt (contiguous)
  hipMemsetAsync(cnt, 0, (102400 + 1024) * sizeof(int), stream);

  // CSR-lite build (bucket level only)
  k_hist<<<392, 256, 0, stream>>>(dst, cnt, bcnt);
  k_dis<<<(NN + 255) / 256, 256, 0, stream>>>(cnt, dis);
  k_bscan<<<1, 1024, 0, stream>>>(bcnt, gbase, gcur);
  k_bin<<<NBB, 512, 0, stream>>>(src, dst, gcur, packed);

  // layer 1
  k_mm<<<4096, 256, 0, stream>>>(x, W1, dis, hs);
  k_agg<<<NBKT, 512, 0, stream>>>(hs, packed, gbase, dis, b1, vbuf);
  // layer 2
  k_mm<<<4096, 256, 0, stream>>>(vbuf, W2, dis, hs);
  k_agg<<<NBKT, 512, 0, stream>>>(hs, packed, gbase, dis, b2, vbuf);
  // head
  k_head<<<4096, 256, 0, stream>>>(vbuf, Wd, bd, Wo, bo, out);
}

// Round 5
// 440.087 us; speedup vs baseline: 3.9101x; 3.9101x over previous
//
#include <hip/hip_runtime.h>

#define NN 100000
#define NE 1600000
#define SHIFT 7
#define BKN 128              // nodes per bucket
#define NBKT 782             // ceil(NN/128)
#define EPB 8192             // edges per k_bin block
#define NBB 196              // ceil(NE/EPB)

// ---- per-bucket histogram (LDS-staged) ----
__global__ __launch_bounds__(256) void k_bcount(const int* __restrict__ dst,
                                                int* __restrict__ bcnt) {
  __shared__ int bh[NBKT];
  for (int i = threadIdx.x; i < NBKT; i += 256) bh[i] = 0;
  __syncthreads();
  for (int e = blockIdx.x * 256 + threadIdx.x; e < NE; e += gridDim.x * 256)
    atomicAdd(&bh[dst[e] >> SHIFT], 1);
  __syncthreads();
  for (int i = threadIdx.x; i < NBKT; i += 256)
    if (bh[i]) atomicAdd(&bcnt[i], bh[i]);
}

// ---- exclusive scan of 782 bucket counts (single block) ----
__global__ __launch_bounds__(1024) void k_bscan(const int* __restrict__ bcnt,
                                                int* __restrict__ gbase,
                                                int* __restrict__ gcur,
                                                int* __restrict__ offs) {
  __shared__ int s[1024];
  int t = threadIdx.x;
  int v = (t < NBKT) ? bcnt[t] : 0;
  s[t] = v;
  __syncthreads();
  for (int off = 1; off < 1024; off <<= 1) {
    int u = (t >= off) ? s[t - off] : 0;
    __syncthreads();
    s[t] += u;
    __syncthreads();
  }
  if (t < NBKT) {
    int excl = s[t] - v;
    gbase[t] = excl;
    gcur[t] = excl;
  }
  if (t == 0) { gbase[NBKT] = NE; offs[NN] = NE; }
}

// ---- bin edges by dst bucket: packed = (dstLocal<<24)|src ----
__global__ __launch_bounds__(512) void k_bin(const int* __restrict__ src,
                                             const int* __restrict__ dst,
                                             int* __restrict__ gcur,
                                             unsigned* __restrict__ packed) {
  __shared__ int lc[NBKT];
  for (int i = threadIdx.x; i < NBKT; i += 512) lc[i] = 0;
  __syncthreads();
  const int base = blockIdx.x * EPB;
  const int end = (base + EPB < NE) ? base + EPB : NE;
  for (int e = base + threadIdx.x; e < end; e += 512)
    atomicAdd(&lc[dst[e] >> SHIFT], 1);
  __syncthreads();
  for (int i = threadIdx.x; i < NBKT; i += 512) {
    int c = lc[i];
    if (c) lc[i] = atomicAdd(&gcur[i], c);  // lc becomes running global cursor
  }
  __syncthreads();
  for (int e = base + threadIdx.x; e < end; e += 512) {
    int d = dst[e];
    int pos = atomicAdd(&lc[d >> SHIFT], 1);
    packed[pos] = ((unsigned)(d & (BKN - 1)) << 24) | (unsigned)src[e];
  }
}

// ---- per-bucket counting sort -> CSR (srcs, offs) + dis ----
__global__ __launch_bounds__(256) void k_csr(const unsigned* __restrict__ packed,
                                             const int* __restrict__ gbase,
                                             int* __restrict__ offs,
                                             float* __restrict__ dis,
                                             int* __restrict__ srcs) {
  __shared__ int lc[BKN];   // counts
  __shared__ int sc[BKN];   // inclusive scan
  __shared__ int cur[BKN];  // scatter cursors
  const int b = blockIdx.x;
  const int tid = threadIdx.x;
  const int nbase = b << SHIFT;
  const int ebase = gbase[b];
  const int ecnt = gbase[b + 1] - ebase;
  if (tid < BKN) lc[tid] = 0;
  __syncthreads();
  for (int e = tid; e < ecnt; e += 256)
    atomicAdd(&lc[packed[ebase + e] >> 24], 1);
  __syncthreads();
  if (tid < BKN) sc[tid] = lc[tid];
  for (int off = 1; off < BKN; off <<= 1) {
    __syncthreads();
    int u = (tid < BKN && tid >= off) ? sc[tid - off] : 0;
    __syncthreads();
    if (tid < BKN) sc[tid] += u;
  }
  __syncthreads();
  if (tid < BKN) {
    int excl = sc[tid] - lc[tid];
    cur[tid] = ebase + excl;
    int node = nbase + tid;
    if (node < NN) {
      offs[node] = ebase + excl;
      dis[node] = rsqrtf((float)lc[tid] + 1.0f);  // deg+1 (self loop)
    }
  }
  __syncthreads();
  for (int e = tid; e < ecnt; e += 256) {
    unsigned p = packed[ebase + e];
    int pos = atomicAdd(&cur[p >> 24], 1);
    srcs[pos] = (int)(p & 0x00FFFFFFu);
  }
}

// ---- 64x64 GEMM: hs = (in @ W) * dis ----
__global__ __launch_bounds__(256) void k_mm(const float* __restrict__ in,
                                            const float* __restrict__ W,
                                            const float* __restrict__ dis,
                                            float* __restrict__ hs) {
  __shared__ float Wl[64 * 64];
  for (int i = threadIdx.x; i < 64 * 64; i += 256) Wl[i] = W[i];
  __syncthreads();
  const int lane = threadIdx.x & 63;
  const int gw = (blockIdx.x * 256 + threadIdx.x) >> 6;
  const int nw = gridDim.x * 4;
  for (int row = gw; row < NN; row += nw) {
    float v = in[row * 64 + lane];
    float acc = 0.0f;
#pragma unroll
    for (int k = 0; k < 64; ++k)
      acc = fmaf(__shfl(v, k), Wl[k * 64 + lane], acc);
    hs[row * 64 + lane] = acc * dis[row];
  }
}

// ---- pure gather: v = relu(dis[t]*(self + sum_edges hs[s]) + b) ----
__global__ __launch_bounds__(256) void k_gather(const float* __restrict__ hs_in,
                                                const int* __restrict__ offs,
                                                const int* __restrict__ srcs,
                                                const float* __restrict__ dis,
                                                const float* __restrict__ b,
                                                float* __restrict__ v_out) {
  const int lane = threadIdx.x & 63;
  const int gw = (blockIdx.x * 256 + threadIdx.x) >> 6;
  const int nw = gridDim.x * 4;
  const float bl = b[lane];
  for (int t = gw; t < NN; t += nw) {
    float sum = hs_in[t * 64 + lane];  // self loop
    const int e1 = offs[t + 1];
    int e = offs[t];
    for (; e + 16 <= e1; e += 16) {
      float a[16];
#pragma unroll
      for (int j = 0; j < 16; ++j) a[j] = hs_in[srcs[e + j] * 64 + lane];
      float s0 = (a[0] + a[1]) + (a[2] + a[3]);
      float s1 = (a[4] + a[5]) + (a[6] + a[7]);
      float s2 = (a[8] + a[9]) + (a[10] + a[11]);
      float s3 = (a[12] + a[13]) + (a[14] + a[15]);
      sum += (s0 + s1) + (s2 + s3);
    }
    if (e + 8 <= e1) {
      float a[8];
#pragma unroll
      for (int j = 0; j < 8; ++j) a[j] = hs_in[srcs[e + j] * 64 + lane];
      sum += ((a[0] + a[1]) + (a[2] + a[3])) + ((a[4] + a[5]) + (a[6] + a[7]));
      e += 8;
    }
    if (e + 4 <= e1) {
      float a[4];
#pragma unroll
      for (int j = 0; j < 4; ++j) a[j] = hs_in[srcs[e + j] * 64 + lane];
      sum += (a[0] + a[1]) + (a[2] + a[3]);
      e += 4;
    }
    for (; e < e1; ++e) sum += hs_in[srcs[e] * 64 + lane];
    v_out[t * 64 + lane] = fmaxf(fmaf(dis[t], sum, bl), 0.0f);
  }
}

// ---- dense head: v2 -> relu(dense128) -> out2 ----
__global__ __launch_bounds__(256) void k_head(const float* __restrict__ v2,
                                              const float* __restrict__ Wd,
                                              const float* __restrict__ bd,
                                              const float* __restrict__ Wo,
                                              const float* __restrict__ bo,
                                              float* __restrict__ out) {
  __shared__ float Wdl[64 * 128];  // 32 KiB
  __shared__ float Wol[256];
  for (int i = threadIdx.x; i < 64 * 128; i += 256) Wdl[i] = Wd[i];
  if (threadIdx.x < 256) Wol[threadIdx.x] = Wo[threadIdx.x];
  __syncthreads();
  const int lane = threadIdx.x & 63;
  const int gw = (blockIdx.x * 256 + threadIdx.x) >> 6;
  const int nw = gridDim.x * 4;
  const float bd0 = bd[lane], bd1 = bd[lane + 64];
  const float bo0 = bo[0], bo1 = bo[1];
  for (int row = gw; row < NN; row += nw) {
    float v = v2[row * 64 + lane];  // already relu'd
    float t0 = bd0, t1 = bd1;
#pragma unroll
    for (int k = 0; k < 64; ++k) {
      const float xk = __shfl(v, k);
      t0 = fmaf(xk, Wdl[k * 128 + lane], t0);
      t1 = fmaf(xk, Wdl[k * 128 + 64 + lane], t1);
    }
    t0 = fmaxf(t0, 0.0f);
    t1 = fmaxf(t1, 0.0f);
    float o0 = fmaf(t0, Wol[lane * 2 + 0], t1 * Wol[(lane + 64) * 2 + 0]);
    float o1 = fmaf(t0, Wol[lane * 2 + 1], t1 * Wol[(lane + 64) * 2 + 1]);
#pragma unroll
    for (int off = 32; off > 0; off >>= 1) {
      o0 += __shfl_down(o0, off);
      o1 += __shfl_down(o1, off);
    }
    if (lane == 0) {
      out[row * 2 + 0] = o0 + bo0;
      out[row * 2 + 1] = o1 + bo1;
    }
  }
}

extern "C" void kernel_launch(void* const* d_in, const int* in_sizes, int n_in,
                              void* d_out, int out_size, void* d_ws, size_t ws_size,
                              hipStream_t stream) {
  const float* x  = (const float*)d_in[0];
  const int*   ei = (const int*)d_in[1];
  const float* W1 = (const float*)d_in[2];
  const float* b1 = (const float*)d_in[3];
  const float* W2 = (const float*)d_in[4];
  const float* b2 = (const float*)d_in[5];
  const float* Wd = (const float*)d_in[6];
  const float* bd = (const float*)d_in[7];
  const float* Wo = (const float*)d_in[8];
  const float* bo = (const float*)d_in[9];
  float* out = (float*)d_out;

  const int* src = ei;        // edge_index[0]
  const int* dst = ei + NE;   // edge_index[1]

  // workspace layout (4 B units)
  char* ws = (char*)d_ws;
  int*      bcnt   = (int*)(ws);                    // 1024
  int*      gbase  = (int*)(ws + 1024L * 4);        // 1024 (NBKT+1 used)
  int*      gcur   = (int*)(ws + 2048L * 4);        // 1024
  int*      offs   = (int*)(ws + 3072L * 4);        // NN+1 (pad to 102912)
  float*    dis    = (float*)(ws + 105984L * 4);    // NN (pad 102400)
  int*      srcs   = (int*)(ws + 208384L * 4);      // NE
  float*    hs     = (float*)(ws + 1808384L * 4);   // NN*64
  unsigned* packed = (unsigned*)hs;                 // NE (dead before k_mm writes hs)
  float*    vbuf   = (float*)(ws + 8208384L * 4);   // NN*64

  // zero bucket counters only (4 KiB)
  hipMemsetAsync(bcnt, 0, 1024 * sizeof(int), stream);

  // CSR build: bucket histogram -> scan -> bin -> per-bucket counting sort
  k_bcount<<<392, 256, 0, stream>>>(dst, bcnt);
  k_bscan<<<1, 1024, 0, stream>>>(bcnt, gbase, gcur, offs);
  k_bin<<<NBB, 512, 0, stream>>>(src, dst, gcur, packed);
  k_csr<<<NBKT, 256, 0, stream>>>(packed, gbase, offs, dis, srcs);

  // layer 1: hs = (x@W1)*dis ; v1 = relu(dis*(gather hs)+b1)
  k_mm<<<4096, 256, 0, stream>>>(x, W1, dis, hs);
  k_gather<<<4096, 256, 0, stream>>>(hs, offs, srcs, dis, b1, vbuf);
  // layer 2
  k_mm<<<4096, 256, 0, stream>>>(vbuf, W2, dis, hs);
  k_gather<<<4096, 256, 0, stream>>>(hs, offs, srcs, dis, b2, vbuf);
  // head
  k_head<<<4096, 256, 0, stream>>>(vbuf, Wd, bd, Wo, bo, out);
}

// Round 6
// 262.835 us; speedup vs baseline: 6.5471x; 1.6744x over previous
//
#include <hip/hip_runtime.h>

#define NN 100000
#define NE 1600000
#define SHIFT 7
#define BKN 128              // nodes per bucket
#define NBKT 782             // ceil(NN/128)
#define EPB 8192             // edges per k_bin block
#define NBB 196              // ceil(NE/EPB)

// ---- per-bucket histogram (LDS-staged) ----
__global__ __launch_bounds__(256) void k_bcount(const int* __restrict__ dst,
                                                int* __restrict__ bcnt) {
  __shared__ int bh[NBKT];
  for (int i = threadIdx.x; i < NBKT; i += 256) bh[i] = 0;
  __syncthreads();
  for (int e = blockIdx.x * 256 + threadIdx.x; e < NE; e += gridDim.x * 256)
    atomicAdd(&bh[dst[e] >> SHIFT], 1);
  __syncthreads();
  for (int i = threadIdx.x; i < NBKT; i += 256)
    if (bh[i]) atomicAdd(&bcnt[i], bh[i]);
}

// ---- exclusive scan of 782 bucket counts (single block) ----
__global__ __launch_bounds__(1024) void k_bscan(const int* __restrict__ bcnt,
                                                int* __restrict__ gbase,
                                                int* __restrict__ gcur,
                                                int* __restrict__ offs) {
  __shared__ int s[1024];
  int t = threadIdx.x;
  int v = (t < NBKT) ? bcnt[t] : 0;
  s[t] = v;
  __syncthreads();
  for (int off = 1; off < 1024; off <<= 1) {
    int u = (t >= off) ? s[t - off] : 0;
    __syncthreads();
    s[t] += u;
    __syncthreads();
  }
  if (t < NBKT) {
    int excl = s[t] - v;
    gbase[t] = excl;
    gcur[t] = excl;
  }
  if (t == 0) { gbase[NBKT] = NE; offs[NN] = NE; }
}

// ---- bin edges by dst bucket: packed = (dstLocal<<24)|src ----
__global__ __launch_bounds__(512) void k_bin(const int* __restrict__ src,
                                             const int* __restrict__ dst,
                                             int* __restrict__ gcur,
                                             unsigned* __restrict__ packed) {
  __shared__ int lc[NBKT];
  for (int i = threadIdx.x; i < NBKT; i += 512) lc[i] = 0;
  __syncthreads();
  const int base = blockIdx.x * EPB;
  const int end = (base + EPB < NE) ? base + EPB : NE;
  for (int e = base + threadIdx.x; e < end; e += 512)
    atomicAdd(&lc[dst[e] >> SHIFT], 1);
  __syncthreads();
  for (int i = threadIdx.x; i < NBKT; i += 512) {
    int c = lc[i];
    if (c) lc[i] = atomicAdd(&gcur[i], c);  // lc becomes running global cursor
  }
  __syncthreads();
  for (int e = base + threadIdx.x; e < end; e += 512) {
    int d = dst[e];
    int pos = atomicAdd(&lc[d >> SHIFT], 1);
    packed[pos] = ((unsigned)(d & (BKN - 1)) << 24) | (unsigned)src[e];
  }
}

// ---- per-bucket counting sort -> CSR (srcs, offs) + dis ----
__global__ __launch_bounds__(256) void k_csr(const unsigned* __restrict__ packed,
                                             const int* __restrict__ gbase,
                                             int* __restrict__ offs,
                                             float* __restrict__ dis,
                                             int* __restrict__ srcs) {
  __shared__ int lc[BKN];   // counts
  __shared__ int sc[BKN];   // inclusive scan
  __shared__ int cur[BKN];  // scatter cursors
  const int b = blockIdx.x;
  const int tid = threadIdx.x;
  const int nbase = b << SHIFT;
  const int ebase = gbase[b];
  const int ecnt = gbase[b + 1] - ebase;
  if (tid < BKN) lc[tid] = 0;
  __syncthreads();
  for (int e = tid; e < ecnt; e += 256)
    atomicAdd(&lc[packed[ebase + e] >> 24], 1);
  __syncthreads();
  if (tid < BKN) sc[tid] = lc[tid];
  for (int off = 1; off < BKN; off <<= 1) {
    __syncthreads();
    int u = (tid < BKN && tid >= off) ? sc[tid - off] : 0;
    __syncthreads();
    if (tid < BKN) sc[tid] += u;
  }
  __syncthreads();
  if (tid < BKN) {
    int excl = sc[tid] - lc[tid];
    cur[tid] = ebase + excl;
    int node = nbase + tid;
    if (node < NN) {
      offs[node] = ebase + excl;
      dis[node] = rsqrtf((float)lc[tid] + 1.0f);  // deg+1 (self loop)
    }
  }
  __syncthreads();
  for (int e = tid; e < ecnt; e += 256) {
    unsigned p = packed[ebase + e];
    int pos = atomicAdd(&cur[p >> 24], 1);
    srcs[pos] = (int)(p & 0x00FFFFFFu);
  }
}

// ---- tiled GEMM: hs[128 rows x 64] = (in @ W) * dis, 4x8 per thread ----
__global__ __launch_bounds__(256) void k_mm(const float* __restrict__ in,
                                            const float* __restrict__ W,
                                            const float* __restrict__ dis,
                                            float* __restrict__ hs) {
  __shared__ float At[64][132];  // A-tile transposed [k][row], pad for banks
  __shared__ float Wl[64][68];   // W [k][col]
  const int tid = threadIdx.x;
  // stage W (64x64 = 1024 float4)
  for (int i = tid; i < 1024; i += 256) {
    const int k = i >> 4, c4 = (i & 15) << 2;
    const float4 w = ((const float4*)W)[i];
    Wl[k][c4] = w.x; Wl[k][c4 + 1] = w.y; Wl[k][c4 + 2] = w.z; Wl[k][c4 + 3] = w.w;
  }
  // stage A-tile (128x64 = 2048 float4), transposed into At
  const int rbase = blockIdx.x << 7;
  for (int i = tid; i < 2048; i += 256) {
    const int row = i >> 4, k4 = (i & 15) << 2;
    const int grow = rbase + row;
    float4 a = make_float4(0.f, 0.f, 0.f, 0.f);
    if (grow < NN) a = ((const float4*)in)[grow * 16 + (i & 15)];
    At[k4][row] = a.x; At[k4 + 1][row] = a.y; At[k4 + 2][row] = a.z; At[k4 + 3][row] = a.w;
  }
  __syncthreads();
  const int r0 = (tid >> 3) << 2;  // 32 row-groups of 4
  const int c0 = (tid & 7) << 3;   // 8 col-groups of 8
  float acc[4][8] = {};
#pragma unroll 8
  for (int k = 0; k < 64; ++k) {
    const float4 av = *(const float4*)&At[k][r0];
    const float4 b0 = *(const float4*)&Wl[k][c0];
    const float4 b1 = *(const float4*)&Wl[k][c0 + 4];
    const float a[4] = {av.x, av.y, av.z, av.w};
    const float bb[8] = {b0.x, b0.y, b0.z, b0.w, b1.x, b1.y, b1.z, b1.w};
#pragma unroll
    for (int i = 0; i < 4; ++i)
#pragma unroll
      for (int j = 0; j < 8; ++j) acc[i][j] = fmaf(a[i], bb[j], acc[i][j]);
  }
#pragma unroll
  for (int i = 0; i < 4; ++i) {
    const int row = rbase + r0 + i;
    if (row < NN) {
      const float d = dis[row];
      float4 o0 = {acc[i][0] * d, acc[i][1] * d, acc[i][2] * d, acc[i][3] * d};
      float4 o1 = {acc[i][4] * d, acc[i][5] * d, acc[i][6] * d, acc[i][7] * d};
      float4* p = (float4*)(hs + row * 64 + c0);
      p[0] = o0; p[1] = o1;
    }
  }
}

// ---- pure gather: v = relu(dis[t]*(self + sum_edges hs[s]) + b) ----
__global__ __launch_bounds__(256) void k_gather(const float* __restrict__ hs_in,
                                                const int* __restrict__ offs,
                                                const int* __restrict__ srcs,
                                                const float* __restrict__ dis,
                                                const float* __restrict__ b,
                                                float* __restrict__ v_out) {
  const int lane = threadIdx.x & 63;
  const int gw = (blockIdx.x * 256 + threadIdx.x) >> 6;
  const int nw = gridDim.x * 4;
  const float bl = b[lane];
  for (int t = gw; t < NN; t += nw) {
    float sum = hs_in[t * 64 + lane];  // self loop
    const int e1 = offs[t + 1];
    int e = offs[t];
    for (; e + 16 <= e1; e += 16) {
      float a[16];
#pragma unroll
      for (int j = 0; j < 16; ++j) a[j] = hs_in[srcs[e + j] * 64 + lane];
      float s0 = (a[0] + a[1]) + (a[2] + a[3]);
      float s1 = (a[4] + a[5]) + (a[6] + a[7]);
      float s2 = (a[8] + a[9]) + (a[10] + a[11]);
      float s3 = (a[12] + a[13]) + (a[14] + a[15]);
      sum += (s0 + s1) + (s2 + s3);
    }
    if (e + 8 <= e1) {
      float a[8];
#pragma unroll
      for (int j = 0; j < 8; ++j) a[j] = hs_in[srcs[e + j] * 64 + lane];
      sum += ((a[0] + a[1]) + (a[2] + a[3])) + ((a[4] + a[5]) + (a[6] + a[7]));
      e += 8;
    }
    if (e + 4 <= e1) {
      float a[4];
#pragma unroll
      for (int j = 0; j < 4; ++j) a[j] = hs_in[srcs[e + j] * 64 + lane];
      sum += (a[0] + a[1]) + (a[2] + a[3]);
      e += 4;
    }
    for (; e < e1; ++e) sum += hs_in[srcs[e] * 64 + lane];
    v_out[t * 64 + lane] = fmaxf(fmaf(dis[t], sum, bl), 0.0f);
  }
}

// ---- tiled head: relu(v2@Wd+bd) @ Wo + bo, 8x8 per thread + reduce ----
__global__ __launch_bounds__(256) void k_head(const float* __restrict__ v2,
                                              const float* __restrict__ Wd,
                                              const float* __restrict__ bd,
                                              const float* __restrict__ Wo,
                                              const float* __restrict__ bo,
                                              float* __restrict__ out) {
  __shared__ float At[64][132];  // v2-tile transposed [k][row]
  __shared__ float Bl[64][132];  // Wd [k][col 0..127]
  __shared__ float Wol[256];     // Wo [128][2]
  __shared__ float bdl[128];
  const int tid = threadIdx.x;
  // stage Wd (64x128 = 2048 float4)
  for (int i = tid; i < 2048; i += 256) {
    const int k = i >> 5, c4 = (i & 31) << 2;
    const float4 w = ((const float4*)Wd)[i];
    Bl[k][c4] = w.x; Bl[k][c4 + 1] = w.y; Bl[k][c4 + 2] = w.z; Bl[k][c4 + 3] = w.w;
  }
  if (tid < 256) Wol[tid] = Wo[tid];
  if (tid < 128) bdl[tid] = bd[tid];
  // stage A-tile (128x64), transposed
  const int rbase = blockIdx.x << 7;
  for (int i = tid; i < 2048; i += 256) {
    const int row = i >> 4, k4 = (i & 15) << 2;
    const int grow = rbase + row;
    float4 a = make_float4(0.f, 0.f, 0.f, 0.f);
    if (grow < NN) a = ((const float4*)v2)[grow * 16 + (i & 15)];
    At[k4][row] = a.x; At[k4 + 1][row] = a.y; At[k4 + 2][row] = a.z; At[k4 + 3][row] = a.w;
  }
  __syncthreads();
  const int r0 = (tid >> 4) << 3;  // 16 row-groups of 8
  const int c0 = (tid & 15) << 3;  // 16 col-groups of 8
  float acc[8][8];
#pragma unroll
  for (int i = 0; i < 8; ++i)
#pragma unroll
    for (int j = 0; j < 8; ++j) acc[i][j] = bdl[c0 + j];
#pragma unroll 4
  for (int k = 0; k < 64; ++k) {
    const float4 a0 = *(const float4*)&At[k][r0];
    const float4 a1 = *(const float4*)&At[k][r0 + 4];
    const float4 b0 = *(const float4*)&Bl[k][c0];
    const float4 b1 = *(const float4*)&Bl[k][c0 + 4];
    const float a[8] = {a0.x, a0.y, a0.z, a0.w, a1.x, a1.y, a1.z, a1.w};
    const float bb[8] = {b0.x, b0.y, b0.z, b0.w, b1.x, b1.y, b1.z, b1.w};
#pragma unroll
    for (int i = 0; i < 8; ++i)
#pragma unroll
      for (int j = 0; j < 8; ++j) acc[i][j] = fmaf(a[i], bb[j], acc[i][j]);
  }
  // relu + project to 2 + reduce across the 16 col-groups (consecutive lanes)
  const float bo0 = bo[0], bo1 = bo[1];
#pragma unroll
  for (int i = 0; i < 8; ++i) {
    float o0 = 0.f, o1 = 0.f;
#pragma unroll
    for (int j = 0; j < 8; ++j) {
      const float t = fmaxf(acc[i][j], 0.f);
      o0 = fmaf(t, Wol[(c0 + j) * 2], o0);
      o1 = fmaf(t, Wol[(c0 + j) * 2 + 1], o1);
    }
#pragma unroll
    for (int m = 1; m < 16; m <<= 1) {
      o0 += __shfl_xor(o0, m);
      o1 += __shfl_xor(o1, m);
    }
    const int row = rbase + r0 + i;
    if ((tid & 15) == 0 && row < NN) {
      out[row * 2 + 0] = o0 + bo0;
      out[row * 2 + 1] = o1 + bo1;
    }
  }
}

extern "C" void kernel_launch(void* const* d_in, const int* in_sizes, int n_in,
                              void* d_out, int out_size, void* d_ws, size_t ws_size,
                              hipStream_t stream) {
  const float* x  = (const float*)d_in[0];
  const int*   ei = (const int*)d_in[1];
  const float* W1 = (const float*)d_in[2];
  const float* b1 = (const float*)d_in[3];
  const float* W2 = (const float*)d_in[4];
  const float* b2 = (const float*)d_in[5];
  const float* Wd = (const float*)d_in[6];
  const float* bd = (const float*)d_in[7];
  const float* Wo = (const float*)d_in[8];
  const float* bo = (const float*)d_in[9];
  float* out = (float*)d_out;

  const int* src = ei;        // edge_index[0]
  const int* dst = ei + NE;   // edge_index[1]

  // workspace layout (4 B units)
  char* ws = (char*)d_ws;
  int*      bcnt   = (int*)(ws);                    // 1024
  int*      gbase  = (int*)(ws + 1024L * 4);        // 1024 (NBKT+1 used)
  int*      gcur   = (int*)(ws + 2048L * 4);        // 1024
  int*      offs   = (int*)(ws + 3072L * 4);        // NN+1 (pad to 102912)
  float*    dis    = (float*)(ws + 105984L * 4);    // NN (pad 102400)
  int*      srcs   = (int*)(ws + 208384L * 4);      // NE
  float*    hs     = (float*)(ws + 1808384L * 4);   // NN*64
  unsigned* packed = (unsigned*)hs;                 // NE (dead before k_mm writes hs)
  float*    vbuf   = (float*)(ws + 8208384L * 4);   // NN*64

  // zero bucket counters only (4 KiB)
  hipMemsetAsync(bcnt, 0, 1024 * sizeof(int), stream);

  // CSR build: bucket histogram -> scan -> bin -> per-bucket counting sort
  k_bcount<<<392, 256, 0, stream>>>(dst, bcnt);
  k_bscan<<<1, 1024, 0, stream>>>(bcnt, gbase, gcur, offs);
  k_bin<<<NBB, 512, 0, stream>>>(src, dst, gcur, packed);
  k_csr<<<NBKT, 256, 0, stream>>>(packed, gbase, offs, dis, srcs);

  // layer 1: hs = (x@W1)*dis ; v1 = relu(dis*(gather hs)+b1)
  k_mm<<<NBKT, 256, 0, stream>>>(x, W1, dis, hs);
  k_gather<<<4096, 256, 0, stream>>>(hs, offs, srcs, dis, b1, vbuf);
  // layer 2
  k_mm<<<NBKT, 256, 0, stream>>>(vbuf, W2, dis, hs);
  k_gather<<<4096, 256, 0, stream>>>(hs, offs, srcs, dis, b2, vbuf);
  // head
  k_head<<<NBKT, 256, 0, stream>>>(vbuf, Wd, bd, Wo, bo, out);
}

// Round 7
// 233.135 us; speedup vs baseline: 7.3811x; 1.1274x over previous
//
#include <hip/hip_runtime.h>

#define NN 100000
#define NE 1600000
#define SHIFT 7
#define BKN 128              // nodes per bucket
#define NBKT 782             // ceil(NN/128)
#define EPB 8192             // edges per k_bin block
#define NBB 196              // ceil(NE/EPB)

typedef unsigned short u16;

__device__ __forceinline__ u16 f2bf(float f) {  // fp32 -> bf16 bits, RNE
  unsigned u = __float_as_uint(f);
  return (u16)((u + 0x7FFFu + ((u >> 16) & 1u)) >> 16);
}
__device__ __forceinline__ float bf2f(u16 v) {  // exact
  return __uint_as_float(((unsigned)v) << 16);
}

// ---- per-bucket histogram (LDS-staged) ----
__global__ __launch_bounds__(256) void k_bcount(const int* __restrict__ dst,
                                                int* __restrict__ bcnt) {
  __shared__ int bh[NBKT];
  for (int i = threadIdx.x; i < NBKT; i += 256) bh[i] = 0;
  __syncthreads();
  for (int e = blockIdx.x * 256 + threadIdx.x; e < NE; e += gridDim.x * 256)
    atomicAdd(&bh[dst[e] >> SHIFT], 1);
  __syncthreads();
  for (int i = threadIdx.x; i < NBKT; i += 256)
    if (bh[i]) atomicAdd(&bcnt[i], bh[i]);
}

// ---- exclusive scan of 782 bucket counts (single block) ----
__global__ __launch_bounds__(1024) void k_bscan(const int* __restrict__ bcnt,
                                                int* __restrict__ gbase,
                                                int* __restrict__ gcur,
                                                int* __restrict__ offs) {
  __shared__ int s[1024];
  int t = threadIdx.x;
  int v = (t < NBKT) ? bcnt[t] : 0;
  s[t] = v;
  __syncthreads();
  for (int off = 1; off < 1024; off <<= 1) {
    int u = (t >= off) ? s[t - off] : 0;
    __syncthreads();
    s[t] += u;
    __syncthreads();
  }
  if (t < NBKT) {
    int excl = s[t] - v;
    gbase[t] = excl;
    gcur[t] = excl;
  }
  if (t == 0) { gbase[NBKT] = NE; offs[NN] = NE; }
}

// ---- bin edges by dst bucket: packed = (dstLocal<<24)|src ----
__global__ __launch_bounds__(512) void k_bin(const int* __restrict__ src,
                                             const int* __restrict__ dst,
                                             int* __restrict__ gcur,
                                             unsigned* __restrict__ packed) {
  __shared__ int lc[NBKT];
  for (int i = threadIdx.x; i < NBKT; i += 512) lc[i] = 0;
  __syncthreads();
  const int base = blockIdx.x * EPB;
  const int end = (base + EPB < NE) ? base + EPB : NE;
  for (int e = base + threadIdx.x; e < end; e += 512)
    atomicAdd(&lc[dst[e] >> SHIFT], 1);
  __syncthreads();
  for (int i = threadIdx.x; i < NBKT; i += 512) {
    int c = lc[i];
    if (c) lc[i] = atomicAdd(&gcur[i], c);  // lc becomes running global cursor
  }
  __syncthreads();
  for (int e = base + threadIdx.x; e < end; e += 512) {
    int d = dst[e];
    int pos = atomicAdd(&lc[d >> SHIFT], 1);
    packed[pos] = ((unsigned)(d & (BKN - 1)) << 24) | (unsigned)src[e];
  }
}

// ---- per-bucket counting sort -> CSR (srcs, offs) + dis ----
__global__ __launch_bounds__(256) void k_csr(const unsigned* __restrict__ packed,
                                             const int* __restrict__ gbase,
                                             int* __restrict__ offs,
                                             float* __restrict__ dis,
                                             int* __restrict__ srcs) {
  __shared__ int lc[BKN];   // counts
  __shared__ int sc[BKN];   // inclusive scan
  __shared__ int cur[BKN];  // scatter cursors
  const int b = blockIdx.x;
  const int tid = threadIdx.x;
  const int nbase = b << SHIFT;
  const int ebase = gbase[b];
  const int ecnt = gbase[b + 1] - ebase;
  if (tid < BKN) lc[tid] = 0;
  __syncthreads();
  for (int e = tid; e < ecnt; e += 256)
    atomicAdd(&lc[packed[ebase + e] >> 24], 1);
  __syncthreads();
  if (tid < BKN) sc[tid] = lc[tid];
  for (int off = 1; off < BKN; off <<= 1) {
    __syncthreads();
    int u = (tid < BKN && tid >= off) ? sc[tid - off] : 0;
    __syncthreads();
    if (tid < BKN) sc[tid] += u;
  }
  __syncthreads();
  if (tid < BKN) {
    int excl = sc[tid] - lc[tid];
    cur[tid] = ebase + excl;
    int node = nbase + tid;
    if (node < NN) {
      offs[node] = ebase + excl;
      dis[node] = rsqrtf((float)lc[tid] + 1.0f);  // deg+1 (self loop)
    }
  }
  __syncthreads();
  for (int e = tid; e < ecnt; e += 256) {
    unsigned p = packed[ebase + e];
    int pos = atomicAdd(&cur[p >> 24], 1);
    srcs[pos] = (int)(p & 0x00FFFFFFu);
  }
}

// ---- tiled GEMM: hs[128 x 64] = bf16((in @ W) * dis), 4x8 per thread ----
__global__ __launch_bounds__(256) void k_mm(const float* __restrict__ in,
                                            const float* __restrict__ W,
                                            const float* __restrict__ dis,
                                            u16* __restrict__ hs) {
  __shared__ float At[64][132];  // A-tile transposed [k][row], pad for banks
  __shared__ float Wl[64][68];   // W [k][col]
  const int tid = threadIdx.x;
  // stage W (64x64 = 1024 float4)
  for (int i = tid; i < 1024; i += 256) {
    const int k = i >> 4, c4 = (i & 15) << 2;
    const float4 w = ((const float4*)W)[i];
    Wl[k][c4] = w.x; Wl[k][c4 + 1] = w.y; Wl[k][c4 + 2] = w.z; Wl[k][c4 + 3] = w.w;
  }
  // stage A-tile (128x64 = 2048 float4), transposed into At
  const int rbase = blockIdx.x << 7;
  for (int i = tid; i < 2048; i += 256) {
    const int row = i >> 4, k4 = (i & 15) << 2;
    const int grow = rbase + row;
    float4 a = make_float4(0.f, 0.f, 0.f, 0.f);
    if (grow < NN) a = ((const float4*)in)[grow * 16 + (i & 15)];
    At[k4][row] = a.x; At[k4 + 1][row] = a.y; At[k4 + 2][row] = a.z; At[k4 + 3][row] = a.w;
  }
  __syncthreads();
  const int r0 = (tid >> 3) << 2;  // 32 row-groups of 4
  const int c0 = (tid & 7) << 3;   // 8 col-groups of 8
  float acc[4][8] = {};
#pragma unroll 8
  for (int k = 0; k < 64; ++k) {
    const float4 av = *(const float4*)&At[k][r0];
    const float4 b0 = *(const float4*)&Wl[k][c0];
    const float4 b1 = *(const float4*)&Wl[k][c0 + 4];
    const float a[4] = {av.x, av.y, av.z, av.w};
    const float bb[8] = {b0.x, b0.y, b0.z, b0.w, b1.x, b1.y, b1.z, b1.w};
#pragma unroll
    for (int i = 0; i < 4; ++i)
#pragma unroll
      for (int j = 0; j < 8; ++j) acc[i][j] = fmaf(a[i], bb[j], acc[i][j]);
  }
#pragma unroll
  for (int i = 0; i < 4; ++i) {
    const int row = rbase + r0 + i;
    if (row < NN) {
      const float d = dis[row];
      uint4 o;
      o.x = (unsigned)f2bf(acc[i][0] * d) | ((unsigned)f2bf(acc[i][1] * d) << 16);
      o.y = (unsigned)f2bf(acc[i][2] * d) | ((unsigned)f2bf(acc[i][3] * d) << 16);
      o.z = (unsigned)f2bf(acc[i][4] * d) | ((unsigned)f2bf(acc[i][5] * d) << 16);
      o.w = (unsigned)f2bf(acc[i][6] * d) | ((unsigned)f2bf(acc[i][7] * d) << 16);
      *(uint4*)(hs + row * 64 + c0) = o;  // 16B aligned (c0 % 8 == 0)
    }
  }
}

// ---- pure gather (bf16 rows): v = relu(dis[t]*(self + sum hs[s]) + b) ----
__global__ __launch_bounds__(256) void k_gather(const u16* __restrict__ hs,
                                                const int* __restrict__ offs,
                                                const int* __restrict__ srcs,
                                                const float* __restrict__ dis,
                                                const float* __restrict__ b,
                                                float* __restrict__ v_out) {
  const int lane = threadIdx.x & 63;
  const int gw = (blockIdx.x * 256 + threadIdx.x) >> 6;
  const int nw = gridDim.x * 4;
  const float bl = b[lane];
  for (int t = gw; t < NN; t += nw) {
    float sum = bf2f(hs[t * 64 + lane]);  // self loop
    const int e1 = offs[t + 1];
    int e = offs[t];
    for (; e + 16 <= e1; e += 16) {
      u16 a[16];
#pragma unroll
      for (int j = 0; j < 16; ++j) a[j] = hs[srcs[e + j] * 64 + lane];
      float s0 = (bf2f(a[0]) + bf2f(a[1])) + (bf2f(a[2]) + bf2f(a[3]));
      float s1 = (bf2f(a[4]) + bf2f(a[5])) + (bf2f(a[6]) + bf2f(a[7]));
      float s2 = (bf2f(a[8]) + bf2f(a[9])) + (bf2f(a[10]) + bf2f(a[11]));
      float s3 = (bf2f(a[12]) + bf2f(a[13])) + (bf2f(a[14]) + bf2f(a[15]));
      sum += (s0 + s1) + (s2 + s3);
    }
    if (e + 8 <= e1) {
      u16 a[8];
#pragma unroll
      for (int j = 0; j < 8; ++j) a[j] = hs[srcs[e + j] * 64 + lane];
      sum += ((bf2f(a[0]) + bf2f(a[1])) + (bf2f(a[2]) + bf2f(a[3]))) +
             ((bf2f(a[4]) + bf2f(a[5])) + (bf2f(a[6]) + bf2f(a[7])));
      e += 8;
    }
    if (e + 4 <= e1) {
      u16 a[4];
#pragma unroll
      for (int j = 0; j < 4; ++j) a[j] = hs[srcs[e + j] * 64 + lane];
      sum += (bf2f(a[0]) + bf2f(a[1])) + (bf2f(a[2]) + bf2f(a[3]));
      e += 4;
    }
    for (; e < e1; ++e) sum += bf2f(hs[srcs[e] * 64 + lane]);
    v_out[t * 64 + lane] = fmaxf(fmaf(dis[t], sum, bl), 0.0f);
  }
}

// ---- tiled head: relu(v2@Wd+bd) @ Wo + bo, 8x8 per thread + reduce ----
__global__ __launch_bounds__(256) void k_head(const float* __restrict__ v2,
                                              const float* __restrict__ Wd,
                                              const float* __restrict__ bd,
                                              const float* __restrict__ Wo,
                                              const float* __restrict__ bo,
                                              float* __restrict__ out) {
  __shared__ float At[64][132];  // v2-tile transposed [k][row]
  __shared__ float Bl[64][132];  // Wd [k][col 0..127]
  __shared__ float Wol[256];     // Wo [128][2]
  __shared__ float bdl[128];
  const int tid = threadIdx.x;
  // stage Wd (64x128 = 2048 float4)
  for (int i = tid; i < 2048; i += 256) {
    const int k = i >> 5, c4 = (i & 31) << 2;
    const float4 w = ((const float4*)Wd)[i];
    Bl[k][c4] = w.x; Bl[k][c4 + 1] = w.y; Bl[k][c4 + 2] = w.z; Bl[k][c4 + 3] = w.w;
  }
  if (tid < 256) Wol[tid] = Wo[tid];
  if (tid < 128) bdl[tid] = bd[tid];
  // stage A-tile (128x64), transposed
  const int rbase = blockIdx.x << 7;
  for (int i = tid; i < 2048; i += 256) {
    const int row = i >> 4, k4 = (i & 15) << 2;
    const int grow = rbase + row;
    float4 a = make_float4(0.f, 0.f, 0.f, 0.f);
    if (grow < NN) a = ((const float4*)v2)[grow * 16 + (i & 15)];
    At[k4][row] = a.x; At[k4 + 1][row] = a.y; At[k4 + 2][row] = a.z; At[k4 + 3][row] = a.w;
  }
  __syncthreads();
  const int r0 = (tid >> 4) << 3;  // 16 row-groups of 8
  const int c0 = (tid & 15) << 3;  // 16 col-groups of 8
  float acc[8][8];
#pragma unroll
  for (int i = 0; i < 8; ++i)
#pragma unroll
    for (int j = 0; j < 8; ++j) acc[i][j] = bdl[c0 + j];
#pragma unroll 4
  for (int k = 0; k < 64; ++k) {
    const float4 a0 = *(const float4*)&At[k][r0];
    const float4 a1 = *(const float4*)&At[k][r0 + 4];
    const float4 b0 = *(const float4*)&Bl[k][c0];
    const float4 b1 = *(const float4*)&Bl[k][c0 + 4];
    const float a[8] = {a0.x, a0.y, a0.z, a0.w, a1.x, a1.y, a1.z, a1.w};
    const float bb[8] = {b0.x, b0.y, b0.z, b0.w, b1.x, b1.y, b1.z, b1.w};
#pragma unroll
    for (int i = 0; i < 8; ++i)
#pragma unroll
      for (int j = 0; j < 8; ++j) acc[i][j] = fmaf(a[i], bb[j], acc[i][j]);
  }
  // relu + project to 2 + reduce across the 16 col-groups (consecutive lanes)
  const float bo0 = bo[0], bo1 = bo[1];
#pragma unroll
  for (int i = 0; i < 8; ++i) {
    float o0 = 0.f, o1 = 0.f;
#pragma unroll
    for (int j = 0; j < 8; ++j) {
      const float t = fmaxf(acc[i][j], 0.f);
      o0 = fmaf(t, Wol[(c0 + j) * 2], o0);
      o1 = fmaf(t, Wol[(c0 + j) * 2 + 1], o1);
    }
#pragma unroll
    for (int m = 1; m < 16; m <<= 1) {
      o0 += __shfl_xor(o0, m);
      o1 += __shfl_xor(o1, m);
    }
    const int row = rbase + r0 + i;
    if ((tid & 15) == 0 && row < NN) {
      out[row * 2 + 0] = o0 + bo0;
      out[row * 2 + 1] = o1 + bo1;
    }
  }
}

extern "C" void kernel_launch(void* const* d_in, const int* in_sizes, int n_in,
                              void* d_out, int out_size, void* d_ws, size_t ws_size,
                              hipStream_t stream) {
  const float* x  = (const float*)d_in[0];
  const int*   ei = (const int*)d_in[1];
  const float* W1 = (const float*)d_in[2];
  const float* b1 = (const float*)d_in[3];
  const float* W2 = (const float*)d_in[4];
  const float* b2 = (const float*)d_in[5];
  const float* Wd = (const float*)d_in[6];
  const float* bd = (const float*)d_in[7];
  const float* Wo = (const float*)d_in[8];
  const float* bo = (const float*)d_in[9];
  float* out = (float*)d_out;

  const int* src = ei;        // edge_index[0]
  const int* dst = ei + NE;   // edge_index[1]

  // workspace layout (4 B units)
  char* ws = (char*)d_ws;
  int*      bcnt   = (int*)(ws);                    // 1024
  int*      gbase  = (int*)(ws + 1024L * 4);        // 1024 (NBKT+1 used)
  int*      gcur   = (int*)(ws + 2048L * 4);        // 1024
  int*      offs   = (int*)(ws + 3072L * 4);        // NN+1 (pad to 102912)
  float*    dis    = (float*)(ws + 105984L * 4);    // NN (pad 102400)
  int*      srcs   = (int*)(ws + 208384L * 4);      // NE
  u16*      hs     = (u16*)(ws + 1808384L * 4);     // NN*64 bf16 (12.8 MB)
  unsigned* packed = (unsigned*)hs;                 // NE ints (dead before k_mm)
  float*    vbuf   = (float*)(ws + 8208384L * 4);   // NN*64 fp32

  // zero bucket counters only (4 KiB)
  hipMemsetAsync(bcnt, 0, 1024 * sizeof(int), stream);

  // CSR build: bucket histogram -> scan -> bin -> per-bucket counting sort
  k_bcount<<<392, 256, 0, stream>>>(dst, bcnt);
  k_bscan<<<1, 1024, 0, stream>>>(bcnt, gbase, gcur, offs);
  k_bin<<<NBB, 512, 0, stream>>>(src, dst, gcur, packed);
  k_csr<<<NBKT, 256, 0, stream>>>(packed, gbase, offs, dis, srcs);

  // layer 1: hs = bf16((x@W1)*dis) ; v1 = relu(dis*(gather hs)+b1)
  k_mm<<<NBKT, 256, 0, stream>>>(x, W1, dis, hs);
  k_gather<<<4096, 256, 0, stream>>>(hs, offs, srcs, dis, b1, vbuf);
  // layer 2
  k_mm<<<NBKT, 256, 0, stream>>>(vbuf, W2, dis, hs);
  k_gather<<<4096, 256, 0, stream>>>(hs, offs, srcs, dis, b2, vbuf);
  // head
  k_head<<<NBKT, 256, 0, stream>>>(vbuf, Wd, bd, Wo, bo, out);
}

// Round 8
// 217.870 us; speedup vs baseline: 7.8983x; 1.0701x over previous
//
#include <hip/hip_runtime.h>

#define NN 100000
#define NE 1600000
#define SHIFT 7
#define BKN 128               // nodes per bucket
#define NBKT 782              // ceil(NN/128)
#define BSTRIDE 3072          // edge slots per bucket (mean 2046, sigma 45)
#define EPB 8192              // edges per k_bin block
#define NBB 196               // ceil(NE/EPB)

typedef unsigned short u16;

__device__ __forceinline__ u16 f2bf(float f) {  // fp32 -> bf16 bits, RNE
  unsigned u = __float_as_uint(f);
  return (u16)((u + 0x7FFFu + ((u >> 16) & 1u)) >> 16);
}
__device__ __forceinline__ float bf2f(u16 v) {  // exact
  return __uint_as_float(((unsigned)v) << 16);
}

// ---- bin edges into fixed-stride bucket regions: packed=(dstLocal<<24)|src
__global__ __launch_bounds__(512) void k_bin(const int* __restrict__ src,
                                             const int* __restrict__ dst,
                                             int* __restrict__ bcur,
                                             unsigned* __restrict__ packed) {
  __shared__ int lc[NBKT];
  for (int i = threadIdx.x; i < NBKT; i += 512) lc[i] = 0;
  __syncthreads();
  const int base = blockIdx.x * EPB;
  const int end = (base + EPB < NE) ? base + EPB : NE;
  for (int e = base + threadIdx.x; e < end; e += 512)
    atomicAdd(&lc[dst[e] >> SHIFT], 1);
  __syncthreads();
  for (int i = threadIdx.x; i < NBKT; i += 512) {
    int c = lc[i];
    if (c) lc[i] = atomicAdd(&bcur[i], c);  // lc becomes within-bucket cursor
  }
  __syncthreads();
  for (int e = base + threadIdx.x; e < end; e += 512) {
    const int d = dst[e];
    const int b = d >> SHIFT;
    const int pos = atomicAdd(&lc[b], 1);
    if (pos < BSTRIDE)
      packed[b * BSTRIDE + pos] = ((unsigned)(d & (BKN - 1)) << 24) | (unsigned)src[e];
  }
}

// ---- per-bucket counting sort -> bucket-strided CSR (srcs, epos) + dis ----
__global__ __launch_bounds__(256) void k_csr(const unsigned* __restrict__ packed,
                                             const int* __restrict__ bcur,
                                             int2* __restrict__ epos,
                                             float* __restrict__ dis,
                                             int* __restrict__ srcs) {
  __shared__ int lc[BKN];   // counts
  __shared__ int sc[BKN];   // inclusive scan
  __shared__ int cur[BKN];  // scatter cursors
  const int b = blockIdx.x;
  const int tid = threadIdx.x;
  const int nbase = b << SHIFT;
  const int ebase = b * BSTRIDE;
  int ecnt = bcur[b];
  if (ecnt > BSTRIDE) ecnt = BSTRIDE;
  if (tid < BKN) lc[tid] = 0;
  __syncthreads();
  for (int e = tid; e < ecnt; e += 256)
    atomicAdd(&lc[packed[ebase + e] >> 24], 1);
  __syncthreads();
  if (tid < BKN) sc[tid] = lc[tid];
  for (int off = 1; off < BKN; off <<= 1) {
    __syncthreads();
    int u = (tid < BKN && tid >= off) ? sc[tid - off] : 0;
    __syncthreads();
    if (tid < BKN) sc[tid] += u;
  }
  __syncthreads();
  if (tid < BKN) {
    const int excl = sc[tid] - lc[tid];
    cur[tid] = ebase + excl;
    const int node = nbase + tid;
    if (node < NN) {
      epos[node] = make_int2(ebase + excl, ebase + excl + lc[tid]);
      dis[node] = rsqrtf((float)lc[tid] + 1.0f);  // deg+1 (self loop)
    }
  }
  __syncthreads();
  for (int e = tid; e < ecnt; e += 256) {
    const unsigned p = packed[ebase + e];
    const int pos = atomicAdd(&cur[p >> 24], 1);
    srcs[pos] = (int)(p & 0x00FFFFFFu);
  }
}

// ---- tiled GEMM: hs[128 x 64] = bf16((in @ W) * dis), 4x8 per thread ----
template <bool IN_BF16>
__global__ __launch_bounds__(256) void k_mm(const void* __restrict__ in_,
                                            const float* __restrict__ W,
                                            const float* __restrict__ dis,
                                            u16* __restrict__ hs) {
  __shared__ float At[64][132];  // A-tile transposed [k][row], pad for banks
  __shared__ float Wl[64][68];   // W [k][col]
  const int tid = threadIdx.x;
  // stage W (64x64 = 1024 float4)
  for (int i = tid; i < 1024; i += 256) {
    const int k = i >> 4, c4 = (i & 15) << 2;
    const float4 w = ((const float4*)W)[i];
    Wl[k][c4] = w.x; Wl[k][c4 + 1] = w.y; Wl[k][c4 + 2] = w.z; Wl[k][c4 + 3] = w.w;
  }
  // stage A-tile (128 rows x 64), transposed into At
  const int rbase = blockIdx.x << 7;
  if (IN_BF16) {
    const u16* in = (const u16*)in_;
    for (int i = tid; i < 1024; i += 256) {   // uint4 = 8 bf16
      const int row = i >> 3, k8 = (i & 7) << 3;
      const int grow = rbase + row;
      uint4 a = make_uint4(0, 0, 0, 0);
      if (grow < NN) a = ((const uint4*)in)[grow * 8 + (i & 7)];
      At[k8 + 0][row] = bf2f((u16)(a.x & 0xFFFF));
      At[k8 + 1][row] = bf2f((u16)(a.x >> 16));
      At[k8 + 2][row] = bf2f((u16)(a.y & 0xFFFF));
      At[k8 + 3][row] = bf2f((u16)(a.y >> 16));
      At[k8 + 4][row] = bf2f((u16)(a.z & 0xFFFF));
      At[k8 + 5][row] = bf2f((u16)(a.z >> 16));
      At[k8 + 6][row] = bf2f((u16)(a.w & 0xFFFF));
      At[k8 + 7][row] = bf2f((u16)(a.w >> 16));
    }
  } else {
    const float* in = (const float*)in_;
    for (int i = tid; i < 2048; i += 256) {
      const int row = i >> 4, k4 = (i & 15) << 2;
      const int grow = rbase + row;
      float4 a = make_float4(0.f, 0.f, 0.f, 0.f);
      if (grow < NN) a = ((const float4*)in)[grow * 16 + (i & 15)];
      At[k4][row] = a.x; At[k4 + 1][row] = a.y; At[k4 + 2][row] = a.z; At[k4 + 3][row] = a.w;
    }
  }
  __syncthreads();
  const int r0 = (tid >> 3) << 2;  // 32 row-groups of 4
  const int c0 = (tid & 7) << 3;   // 8 col-groups of 8
  float acc[4][8] = {};
#pragma unroll 8
  for (int k = 0; k < 64; ++k) {
    const float4 av = *(const float4*)&At[k][r0];
    const float4 b0 = *(const float4*)&Wl[k][c0];
    const float4 b1 = *(const float4*)&Wl[k][c0 + 4];
    const float a[4] = {av.x, av.y, av.z, av.w};
    const float bb[8] = {b0.x, b0.y, b0.z, b0.w, b1.x, b1.y, b1.z, b1.w};
#pragma unroll
    for (int i = 0; i < 4; ++i)
#pragma unroll
      for (int j = 0; j < 8; ++j) acc[i][j] = fmaf(a[i], bb[j], acc[i][j]);
  }
#pragma unroll
  for (int i = 0; i < 4; ++i) {
    const int row = rbase + r0 + i;
    if (row < NN) {
      const float d = dis[row];
      uint4 o;
      o.x = (unsigned)f2bf(acc[i][0] * d) | ((unsigned)f2bf(acc[i][1] * d) << 16);
      o.y = (unsigned)f2bf(acc[i][2] * d) | ((unsigned)f2bf(acc[i][3] * d) << 16);
      o.z = (unsigned)f2bf(acc[i][4] * d) | ((unsigned)f2bf(acc[i][5] * d) << 16);
      o.w = (unsigned)f2bf(acc[i][6] * d) | ((unsigned)f2bf(acc[i][7] * d) << 16);
      *(uint4*)(hs + row * 64 + c0) = o;
    }
  }
}

// ---- pure gather (bf16 rows): v = bf16(relu(dis[t]*(self+sum)+b)) ----
__global__ __launch_bounds__(256) void k_gather(const u16* __restrict__ hs,
                                                const int2* __restrict__ epos,
                                                const int* __restrict__ srcs,
                                                const float* __restrict__ dis,
                                                const float* __restrict__ b,
                                                u16* __restrict__ v_out) {
  const int lane = threadIdx.x & 63;
  const int gw = (blockIdx.x * 256 + threadIdx.x) >> 6;
  const int nw = gridDim.x * 4;
  const float bl = b[lane];
  for (int t = gw; t < NN; t += nw) {
    float sum = bf2f(hs[t * 64 + lane]);  // self loop
    const int2 ep = epos[t];
    int e = ep.x;
    const int e1 = ep.y;
    for (; e + 16 <= e1; e += 16) {
      u16 a[16];
#pragma unroll
      for (int j = 0; j < 16; ++j) a[j] = hs[srcs[e + j] * 64 + lane];
      float s0 = (bf2f(a[0]) + bf2f(a[1])) + (bf2f(a[2]) + bf2f(a[3]));
      float s1 = (bf2f(a[4]) + bf2f(a[5])) + (bf2f(a[6]) + bf2f(a[7]));
      float s2 = (bf2f(a[8]) + bf2f(a[9])) + (bf2f(a[10]) + bf2f(a[11]));
      float s3 = (bf2f(a[12]) + bf2f(a[13])) + (bf2f(a[14]) + bf2f(a[15]));
      sum += (s0 + s1) + (s2 + s3);
    }
    if (e + 8 <= e1) {
      u16 a[8];
#pragma unroll
      for (int j = 0; j < 8; ++j) a[j] = hs[srcs[e + j] * 64 + lane];
      sum += ((bf2f(a[0]) + bf2f(a[1])) + (bf2f(a[2]) + bf2f(a[3]))) +
             ((bf2f(a[4]) + bf2f(a[5])) + (bf2f(a[6]) + bf2f(a[7])));
      e += 8;
    }
    if (e + 4 <= e1) {
      u16 a[4];
#pragma unroll
      for (int j = 0; j < 4; ++j) a[j] = hs[srcs[e + j] * 64 + lane];
      sum += (bf2f(a[0]) + bf2f(a[1])) + (bf2f(a[2]) + bf2f(a[3]));
      e += 4;
    }
    for (; e < e1; ++e) sum += bf2f(hs[srcs[e] * 64 + lane]);
    v_out[t * 64 + lane] = f2bf(fmaxf(fmaf(dis[t], sum, bl), 0.0f));
  }
}

// ---- tiled head: relu(v2@Wd+bd) @ Wo + bo, 8x8 per thread + reduce ----
__global__ __launch_bounds__(256) void k_head(const u16* __restrict__ v2,
                                              const float* __restrict__ Wd,
                                              const float* __restrict__ bd,
                                              const float* __restrict__ Wo,
                                              const float* __restrict__ bo,
                                              float* __restrict__ out) {
  __shared__ float At[64][132];  // v2-tile transposed [k][row]
  __shared__ float Bl[64][132];  // Wd [k][col 0..127]
  __shared__ float Wol[256];     // Wo [128][2]
  __shared__ float bdl[128];
  const int tid = threadIdx.x;
  // stage Wd (64x128 = 2048 float4)
  for (int i = tid; i < 2048; i += 256) {
    const int k = i >> 5, c4 = (i & 31) << 2;
    const float4 w = ((const float4*)Wd)[i];
    Bl[k][c4] = w.x; Bl[k][c4 + 1] = w.y; Bl[k][c4 + 2] = w.z; Bl[k][c4 + 3] = w.w;
  }
  if (tid < 256) Wol[tid] = Wo[tid];
  if (tid < 128) bdl[tid] = bd[tid];
  // stage A-tile (128x64 bf16), transposed
  const int rbase = blockIdx.x << 7;
  for (int i = tid; i < 1024; i += 256) {
    const int row = i >> 3, k8 = (i & 7) << 3;
    const int grow = rbase + row;
    uint4 a = make_uint4(0, 0, 0, 0);
    if (grow < NN) a = ((const uint4*)v2)[grow * 8 + (i & 7)];
    At[k8 + 0][row] = bf2f((u16)(a.x & 0xFFFF));
    At[k8 + 1][row] = bf2f((u16)(a.x >> 16));
    At[k8 + 2][row] = bf2f((u16)(a.y & 0xFFFF));
    At[k8 + 3][row] = bf2f((u16)(a.y >> 16));
    At[k8 + 4][row] = bf2f((u16)(a.z & 0xFFFF));
    At[k8 + 5][row] = bf2f((u16)(a.z >> 16));
    At[k8 + 6][row] = bf2f((u16)(a.w & 0xFFFF));
    At[k8 + 7][row] = bf2f((u16)(a.w >> 16));
  }
  __syncthreads();
  const int r0 = (tid >> 4) << 3;  // 16 row-groups of 8
  const int c0 = (tid & 15) << 3;  // 16 col-groups of 8
  float acc[8][8];
#pragma unroll
  for (int i = 0; i < 8; ++i)
#pragma unroll
    for (int j = 0; j < 8; ++j) acc[i][j] = bdl[c0 + j];
#pragma unroll 4
  for (int k = 0; k < 64; ++k) {
    const float4 a0 = *(const float4*)&At[k][r0];
    const float4 a1 = *(const float4*)&At[k][r0 + 4];
    const float4 b0 = *(const float4*)&Bl[k][c0];
    const float4 b1 = *(const float4*)&Bl[k][c0 + 4];
    const float a[8] = {a0.x, a0.y, a0.z, a0.w, a1.x, a1.y, a1.z, a1.w};
    const float bb[8] = {b0.x, b0.y, b0.z, b0.w, b1.x, b1.y, b1.z, b1.w};
#pragma unroll
    for (int i = 0; i < 8; ++i)
#pragma unroll
      for (int j = 0; j < 8; ++j) acc[i][j] = fmaf(a[i], bb[j], acc[i][j]);
  }
  const float bo0 = bo[0], bo1 = bo[1];
#pragma unroll
  for (int i = 0; i < 8; ++i) {
    float o0 = 0.f, o1 = 0.f;
#pragma unroll
    for (int j = 0; j < 8; ++j) {
      const float t = fmaxf(acc[i][j], 0.f);
      o0 = fmaf(t, Wol[(c0 + j) * 2], o0);
      o1 = fmaf(t, Wol[(c0 + j) * 2 + 1], o1);
    }
#pragma unroll
    for (int m = 1; m < 16; m <<= 1) {
      o0 += __shfl_xor(o0, m);
      o1 += __shfl_xor(o1, m);
    }
    const int row = rbase + r0 + i;
    if ((tid & 15) == 0 && row < NN) {
      out[row * 2 + 0] = o0 + bo0;
      out[row * 2 + 1] = o1 + bo1;
    }
  }
}

extern "C" void kernel_launch(void* const* d_in, const int* in_sizes, int n_in,
                              void* d_out, int out_size, void* d_ws, size_t ws_size,
                              hipStream_t stream) {
  const float* x  = (const float*)d_in[0];
  const int*   ei = (const int*)d_in[1];
  const float* W1 = (const float*)d_in[2];
  const float* b1 = (const float*)d_in[3];
  const float* W2 = (const float*)d_in[4];
  const float* b2 = (const float*)d_in[5];
  const float* Wd = (const float*)d_in[6];
  const float* bd = (const float*)d_in[7];
  const float* Wo = (const float*)d_in[8];
  const float* bo = (const float*)d_in[9];
  float* out = (float*)d_out;

  const int* src = ei;        // edge_index[0]
  const int* dst = ei + NE;   // edge_index[1]

  // workspace layout (4 B units)
  char* ws = (char*)d_ws;
  int*      bcur  = (int*)(ws);                      // [0, 1024)
  int2*     epos  = (int2*)(ws + 1024L * 4);         // NN int2 -> 204800 ints
  float*    dis   = (float*)(ws + 205824L * 4);      // NN (pad 102400)
  int*      srcs  = (int*)(ws + 308224L * 4);        // NBKT*BSTRIDE = 2402304
  u16*      hs    = (u16*)(ws + 2710528L * 4);       // NN*64 bf16 (12.8 MB)
  unsigned* packed = (unsigned*)hs;                  // NBKT*BSTRIDE ints (9.6 MB, dead before k_mm)
  u16*      vbuf  = (u16*)(ws + 5912832L * 4);       // NN*64 bf16

  // zero per-bucket cursors (4 KiB)
  hipMemsetAsync(bcur, 0, 1024 * sizeof(int), stream);

  // CSR build: bin into fixed-stride buckets -> per-bucket counting sort
  k_bin<<<NBB, 512, 0, stream>>>(src, dst, bcur, packed);
  k_csr<<<NBKT, 256, 0, stream>>>(packed, bcur, epos, dis, srcs);

  // layer 1: hs = bf16((x@W1)*dis) ; v1 = bf16(relu(dis*(gather hs)+b1))
  k_mm<false><<<NBKT, 256, 0, stream>>>(x, W1, dis, hs);
  k_gather<<<4096, 256, 0, stream>>>(hs, epos, srcs, dis, b1, vbuf);
  // layer 2
  k_mm<true><<<NBKT, 256, 0, stream>>>(vbuf, W2, dis, hs);
  k_gather<<<4096, 256, 0, stream>>>(hs, epos, srcs, dis, b2, vbuf);
  // head
  k_head<<<NBKT, 256, 0, stream>>>(vbuf, Wd, bd, Wo, bo, out);
}

// Round 9
// 202.596 us; speedup vs baseline: 8.4938x; 1.0754x over previous
//
#include <hip/hip_runtime.h>

#define NN 100000
#define NE 1600000
#define SHIFT 7
#define BKN 128               // nodes per bucket
#define NBKT 782              // ceil(NN/128)
#define BSTRIDE 3072          // edge slots per bucket (mean 2046, sigma 45)
#define EPB 8192              // edges per k_bin block
#define NBB 196               // ceil(NE/EPB)

typedef unsigned short u16;

__device__ __forceinline__ u16 f2bf(float f) {  // fp32 -> bf16 bits, RNE
  unsigned u = __float_as_uint(f);
  return (u16)((u + 0x7FFFu + ((u >> 16) & 1u)) >> 16);
}
__device__ __forceinline__ float bf2f(u16 v) {  // exact
  return __uint_as_float(((unsigned)v) << 16);
}

// ---- bin edges into fixed-stride bucket regions: packed=(dstLocal<<24)|src
__global__ __launch_bounds__(512) void k_bin(const int* __restrict__ src,
                                             const int* __restrict__ dst,
                                             int* __restrict__ bcur,
                                             unsigned* __restrict__ packed) {
  __shared__ int lc[NBKT];
  for (int i = threadIdx.x; i < NBKT; i += 512) lc[i] = 0;
  __syncthreads();
  const int base = blockIdx.x * EPB;
  const int end = (base + EPB < NE) ? base + EPB : NE;
  for (int e = base + threadIdx.x; e < end; e += 512)
    atomicAdd(&lc[dst[e] >> SHIFT], 1);
  __syncthreads();
  for (int i = threadIdx.x; i < NBKT; i += 512) {
    int c = lc[i];
    if (c) lc[i] = atomicAdd(&bcur[i], c);  // lc becomes within-bucket cursor
  }
  __syncthreads();
  for (int e = base + threadIdx.x; e < end; e += 512) {
    const int d = dst[e];
    const int b = d >> SHIFT;
    const int pos = atomicAdd(&lc[b], 1);
    if (pos < BSTRIDE)
      packed[b * BSTRIDE + pos] = ((unsigned)(d & (BKN - 1)) << 24) | (unsigned)src[e];
  }
}

// ---- per-bucket counting sort -> bucket-strided CSR (srcs, epos) + dis ----
__global__ __launch_bounds__(256) void k_csr(const unsigned* __restrict__ packed,
                                             const int* __restrict__ bcur,
                                             int2* __restrict__ epos,
                                             float* __restrict__ dis,
                                             int* __restrict__ srcs) {
  __shared__ int lc[BKN];   // counts
  __shared__ int sc[BKN];   // inclusive scan
  __shared__ int cur[BKN];  // scatter cursors
  const int b = blockIdx.x;
  const int tid = threadIdx.x;
  const int nbase = b << SHIFT;
  const int ebase = b * BSTRIDE;
  int ecnt = bcur[b];
  if (ecnt > BSTRIDE) ecnt = BSTRIDE;
  if (tid < BKN) lc[tid] = 0;
  __syncthreads();
  for (int e = tid; e < ecnt; e += 256)
    atomicAdd(&lc[packed[ebase + e] >> 24], 1);
  __syncthreads();
  if (tid < BKN) sc[tid] = lc[tid];
  for (int off = 1; off < BKN; off <<= 1) {
    __syncthreads();
    int u = (tid < BKN && tid >= off) ? sc[tid - off] : 0;
    __syncthreads();
    if (tid < BKN) sc[tid] += u;
  }
  __syncthreads();
  if (tid < BKN) {
    const int excl = sc[tid] - lc[tid];
    cur[tid] = ebase + excl;
    const int node = nbase + tid;
    if (node < NN) {
      epos[node] = make_int2(ebase + excl, ebase + excl + lc[tid]);
      dis[node] = rsqrtf((float)lc[tid] + 1.0f);  // deg+1 (self loop)
    }
  }
  __syncthreads();
  for (int e = tid; e < ecnt; e += 256) {
    const unsigned p = packed[ebase + e];
    const int pos = atomicAdd(&cur[p >> 24], 1);
    srcs[pos] = (int)(p & 0x00FFFFFFu);
  }
}

// ---- tiled GEMM: hs[128 x 64] = bf16((in @ W) * dis), 4x8 per thread ----
template <bool IN_BF16>
__global__ __launch_bounds__(256) void k_mm(const void* __restrict__ in_,
                                            const float* __restrict__ W,
                                            const float* __restrict__ dis,
                                            u16* __restrict__ hs) {
  __shared__ float At[64][132];  // A-tile transposed [k][row], pad for banks
  __shared__ float Wl[64][68];   // W [k][col]
  const int tid = threadIdx.x;
  // stage W (64x64 = 1024 float4)
  for (int i = tid; i < 1024; i += 256) {
    const int k = i >> 4, c4 = (i & 15) << 2;
    const float4 w = ((const float4*)W)[i];
    Wl[k][c4] = w.x; Wl[k][c4 + 1] = w.y; Wl[k][c4 + 2] = w.z; Wl[k][c4 + 3] = w.w;
  }
  // stage A-tile (128 rows x 64), transposed into At
  const int rbase = blockIdx.x << 7;
  if (IN_BF16) {
    const u16* in = (const u16*)in_;
    for (int i = tid; i < 1024; i += 256) {   // uint4 = 8 bf16
      const int row = i >> 3, k8 = (i & 7) << 3;
      const int grow = rbase + row;
      uint4 a = make_uint4(0, 0, 0, 0);
      if (grow < NN) a = ((const uint4*)in)[grow * 8 + (i & 7)];
      At[k8 + 0][row] = bf2f((u16)(a.x & 0xFFFF));
      At[k8 + 1][row] = bf2f((u16)(a.x >> 16));
      At[k8 + 2][row] = bf2f((u16)(a.y & 0xFFFF));
      At[k8 + 3][row] = bf2f((u16)(a.y >> 16));
      At[k8 + 4][row] = bf2f((u16)(a.z & 0xFFFF));
      At[k8 + 5][row] = bf2f((u16)(a.z >> 16));
      At[k8 + 6][row] = bf2f((u16)(a.w & 0xFFFF));
      At[k8 + 7][row] = bf2f((u16)(a.w >> 16));
    }
  } else {
    const float* in = (const float*)in_;
    for (int i = tid; i < 2048; i += 256) {
      const int row = i >> 4, k4 = (i & 15) << 2;
      const int grow = rbase + row;
      float4 a = make_float4(0.f, 0.f, 0.f, 0.f);
      if (grow < NN) a = ((const float4*)in)[grow * 16 + (i & 15)];
      At[k4][row] = a.x; At[k4 + 1][row] = a.y; At[k4 + 2][row] = a.z; At[k4 + 3][row] = a.w;
    }
  }
  __syncthreads();
  const int r0 = (tid >> 3) << 2;  // 32 row-groups of 4
  const int c0 = (tid & 7) << 3;   // 8 col-groups of 8
  float acc[4][8] = {};
#pragma unroll 8
  for (int k = 0; k < 64; ++k) {
    const float4 av = *(const float4*)&At[k][r0];
    const float4 b0 = *(const float4*)&Wl[k][c0];
    const float4 b1 = *(const float4*)&Wl[k][c0 + 4];
    const float a[4] = {av.x, av.y, av.z, av.w};
    const float bb[8] = {b0.x, b0.y, b0.z, b0.w, b1.x, b1.y, b1.z, b1.w};
#pragma unroll
    for (int i = 0; i < 4; ++i)
#pragma unroll
      for (int j = 0; j < 8; ++j) acc[i][j] = fmaf(a[i], bb[j], acc[i][j]);
  }
#pragma unroll
  for (int i = 0; i < 4; ++i) {
    const int row = rbase + r0 + i;
    if (row < NN) {
      const float d = dis[row];
      uint4 o;
      o.x = (unsigned)f2bf(acc[i][0] * d) | ((unsigned)f2bf(acc[i][1] * d) << 16);
      o.y = (unsigned)f2bf(acc[i][2] * d) | ((unsigned)f2bf(acc[i][3] * d) << 16);
      o.z = (unsigned)f2bf(acc[i][4] * d) | ((unsigned)f2bf(acc[i][5] * d) << 16);
      o.w = (unsigned)f2bf(acc[i][6] * d) | ((unsigned)f2bf(acc[i][7] * d) << 16);
      *(uint4*)(hs + row * 64 + c0) = o;
    }
  }
}

// ---- paired-edge gather: lanes 0-31 = even edge, 32-63 = odd edge ----
// Each lane loads a dword (2 bf16 channels); shfl_xor(32) merges halves.
__global__ __launch_bounds__(256) void k_gather(const u16* __restrict__ hs,
                                                const int2* __restrict__ epos,
                                                const int* __restrict__ srcs,
                                                const float* __restrict__ dis,
                                                const float* __restrict__ b,
                                                u16* __restrict__ v_out) {
  const unsigned* hs32 = (const unsigned*)hs;
  unsigned* vo32 = (unsigned*)v_out;
  const int lane = threadIdx.x & 63;
  const int laneL = lane & 31;   // channel pair index
  const int half = lane >> 5;    // edge parity handled by this half-wave
  const int gw = (blockIdx.x * 256 + threadIdx.x) >> 6;
  const int nw = gridDim.x * 4;
  const float2 bp = ((const float2*)b)[laneL];
  for (int t = gw; t < NN; t += nw) {
    const int2 ep = epos[t];
    int e = ep.x;
    const int e1 = ep.y;
    // self loop (counted once: half 0 only)
    const unsigned sv = hs32[t * 32 + laneL];
    float sum0 = half ? 0.f : bf2f((u16)(sv & 0xFFFF));
    float sum1 = half ? 0.f : bf2f((u16)(sv >> 16));
    for (; e + 32 <= e1; e += 32) {  // 16 dword loads = 32 edges in flight
      unsigned vv[16];
#pragma unroll
      for (int j = 0; j < 16; ++j)
        vv[j] = hs32[srcs[e + 2 * j + half] * 32 + laneL];
#pragma unroll
      for (int j = 0; j < 16; ++j) {
        sum0 += bf2f((u16)(vv[j] & 0xFFFF));
        sum1 += bf2f((u16)(vv[j] >> 16));
      }
    }
    if (e + 16 <= e1) {
      unsigned vv[8];
#pragma unroll
      for (int j = 0; j < 8; ++j)
        vv[j] = hs32[srcs[e + 2 * j + half] * 32 + laneL];
#pragma unroll
      for (int j = 0; j < 8; ++j) {
        sum0 += bf2f((u16)(vv[j] & 0xFFFF));
        sum1 += bf2f((u16)(vv[j] >> 16));
      }
      e += 16;
    }
    if (e + 8 <= e1) {
      unsigned vv[4];
#pragma unroll
      for (int j = 0; j < 4; ++j)
        vv[j] = hs32[srcs[e + 2 * j + half] * 32 + laneL];
#pragma unroll
      for (int j = 0; j < 4; ++j) {
        sum0 += bf2f((u16)(vv[j] & 0xFFFF));
        sum1 += bf2f((u16)(vv[j] >> 16));
      }
      e += 8;
    }
    if (e + 4 <= e1) {
      unsigned vv[2];
#pragma unroll
      for (int j = 0; j < 2; ++j)
        vv[j] = hs32[srcs[e + 2 * j + half] * 32 + laneL];
#pragma unroll
      for (int j = 0; j < 2; ++j) {
        sum0 += bf2f((u16)(vv[j] & 0xFFFF));
        sum1 += bf2f((u16)(vv[j] >> 16));
      }
      e += 4;
    }
    if (e + 2 <= e1) {
      const unsigned v = hs32[srcs[e + half] * 32 + laneL];
      sum0 += bf2f((u16)(v & 0xFFFF));
      sum1 += bf2f((u16)(v >> 16));
      e += 2;
    }
    if (e < e1) {  // last odd edge: count once
      const unsigned v = hs32[srcs[e] * 32 + laneL];
      if (!half) {
        sum0 += bf2f((u16)(v & 0xFFFF));
        sum1 += bf2f((u16)(v >> 16));
      }
    }
    sum0 += __shfl_xor(sum0, 32);
    sum1 += __shfl_xor(sum1, 32);
    if (!half) {
      const float d = dis[t];
      const float r0 = fmaxf(fmaf(d, sum0, bp.x), 0.0f);
      const float r1 = fmaxf(fmaf(d, sum1, bp.y), 0.0f);
      vo32[t * 32 + laneL] = (unsigned)f2bf(r0) | ((unsigned)f2bf(r1) << 16);
    }
  }
}

// ---- tiled head: relu(v2@Wd+bd) @ Wo + bo, 8x8 per thread + reduce ----
__global__ __launch_bounds__(256) void k_head(const u16* __restrict__ v2,
                                              const float* __restrict__ Wd,
                                              const float* __restrict__ bd,
                                              const float* __restrict__ Wo,
                                              const float* __restrict__ bo,
                                              float* __restrict__ out) {
  __shared__ float At[64][132];  // v2-tile transposed [k][row]
  __shared__ float Bl[64][132];  // Wd [k][col 0..127]
  __shared__ float Wol[256];     // Wo [128][2]
  __shared__ float bdl[128];
  const int tid = threadIdx.x;
  // stage Wd (64x128 = 2048 float4)
  for (int i = tid; i < 2048; i += 256) {
    const int k = i >> 5, c4 = (i & 31) << 2;
    const float4 w = ((const float4*)Wd)[i];
    Bl[k][c4] = w.x; Bl[k][c4 + 1] = w.y; Bl[k][c4 + 2] = w.z; Bl[k][c4 + 3] = w.w;
  }
  if (tid < 256) Wol[tid] = Wo[tid];
  if (tid < 128) bdl[tid] = bd[tid];
  // stage A-tile (128x64 bf16), transposed
  const int rbase = blockIdx.x << 7;
  for (int i = tid; i < 1024; i += 256) {
    const int row = i >> 3, k8 = (i & 7) << 3;
    const int grow = rbase + row;
    uint4 a = make_uint4(0, 0, 0, 0);
    if (grow < NN) a = ((const uint4*)v2)[grow * 8 + (i & 7)];
    At[k8 + 0][row] = bf2f((u16)(a.x & 0xFFFF));
    At[k8 + 1][row] = bf2f((u16)(a.x >> 16));
    At[k8 + 2][row] = bf2f((u16)(a.y & 0xFFFF));
    At[k8 + 3][row] = bf2f((u16)(a.y >> 16));
    At[k8 + 4][row] = bf2f((u16)(a.z & 0xFFFF));
    At[k8 + 5][row] = bf2f((u16)(a.z >> 16));
    At[k8 + 6][row] = bf2f((u16)(a.w & 0xFFFF));
    At[k8 + 7][row] = bf2f((u16)(a.w >> 16));
  }
  __syncthreads();
  const int r0 = (tid >> 4) << 3;  // 16 row-groups of 8
  const int c0 = (tid & 15) << 3;  // 16 col-groups of 8
  float acc[8][8];
#pragma unroll
  for (int i = 0; i < 8; ++i)
#pragma unroll
    for (int j = 0; j < 8; ++j) acc[i][j] = bdl[c0 + j];
#pragma unroll 4
  for (int k = 0; k < 64; ++k) {
    const float4 a0 = *(const float4*)&At[k][r0];
    const float4 a1 = *(const float4*)&At[k][r0 + 4];
    const float4 b0 = *(const float4*)&Bl[k][c0];
    const float4 b1 = *(const float4*)&Bl[k][c0 + 4];
    const float a[8] = {a0.x, a0.y, a0.z, a0.w, a1.x, a1.y, a1.z, a1.w};
    const float bb[8] = {b0.x, b0.y, b0.z, b0.w, b1.x, b1.y, b1.z, b1.w};
#pragma unroll
    for (int i = 0; i < 8; ++i)
#pragma unroll
      for (int j = 0; j < 8; ++j) acc[i][j] = fmaf(a[i], bb[j], acc[i][j]);
  }
  const float bo0 = bo[0], bo1 = bo[1];
#pragma unroll
  for (int i = 0; i < 8; ++i) {
    float o0 = 0.f, o1 = 0.f;
#pragma unroll
    for (int j = 0; j < 8; ++j) {
      const float t = fmaxf(acc[i][j], 0.f);
      o0 = fmaf(t, Wol[(c0 + j) * 2], o0);
      o1 = fmaf(t, Wol[(c0 + j) * 2 + 1], o1);
    }
#pragma unroll
    for (int m = 1; m < 16; m <<= 1) {
      o0 += __shfl_xor(o0, m);
      o1 += __shfl_xor(o1, m);
    }
    const int row = rbase + r0 + i;
    if ((tid & 15) == 0 && row < NN) {
      out[row * 2 + 0] = o0 + bo0;
      out[row * 2 + 1] = o1 + bo1;
    }
  }
}

extern "C" void kernel_launch(void* const* d_in, const int* in_sizes, int n_in,
                              void* d_out, int out_size, void* d_ws, size_t ws_size,
                              hipStream_t stream) {
  const float* x  = (const float*)d_in[0];
  const int*   ei = (const int*)d_in[1];
  const float* W1 = (const float*)d_in[2];
  const float* b1 = (const float*)d_in[3];
  const float* W2 = (const float*)d_in[4];
  const float* b2 = (const float*)d_in[5];
  const float* Wd = (const float*)d_in[6];
  const float* bd = (const float*)d_in[7];
  const float* Wo = (const float*)d_in[8];
  const float* bo = (const float*)d_in[9];
  float* out = (float*)d_out;

  const int* src = ei;        // edge_index[0]
  const int* dst = ei + NE;   // edge_index[1]

  // workspace layout (4 B units)
  char* ws = (char*)d_ws;
  int*      bcur  = (int*)(ws);                      // [0, 1024)
  int2*     epos  = (int2*)(ws + 1024L * 4);         // NN int2 -> 204800 ints
  float*    dis   = (float*)(ws + 205824L * 4);      // NN (pad 102400)
  int*      srcs  = (int*)(ws + 308224L * 4);        // NBKT*BSTRIDE = 2402304
  u16*      hs    = (u16*)(ws + 2710528L * 4);       // NN*64 bf16 (12.8 MB)
  unsigned* packed = (unsigned*)hs;                  // NBKT*BSTRIDE ints (9.6 MB, dead before k_mm)
  u16*      vbuf  = (u16*)(ws + 5912832L * 4);       // NN*64 bf16

  // zero per-bucket cursors (4 KiB)
  hipMemsetAsync(bcur, 0, 1024 * sizeof(int), stream);

  // CSR build: bin into fixed-stride buckets -> per-bucket counting sort
  k_bin<<<NBB, 512, 0, stream>>>(src, dst, bcur, packed);
  k_csr<<<NBKT, 256, 0, stream>>>(packed, bcur, epos, dis, srcs);

  // layer 1: hs = bf16((x@W1)*dis) ; v1 = bf16(relu(dis*(gather hs)+b1))
  k_mm<false><<<NBKT, 256, 0, stream>>>(x, W1, dis, hs);
  k_gather<<<4096, 256, 0, stream>>>(hs, epos, srcs, dis, b1, vbuf);
  // layer 2
  k_mm<true><<<NBKT, 256, 0, stream>>>(vbuf, W2, dis, hs);
  k_gather<<<4096, 256, 0, stream>>>(hs, epos, srcs, dis, b2, vbuf);
  // head
  k_head<<<NBKT, 256, 0, stream>>>(vbuf, Wd, bd, Wo, bo, out);
}